// Round 10
// baseline (438.448 us; speedup 1.0000x reference)
//
#include <hip/hip_runtime.h>
#include <hip/hip_bf16.h>

// Problem constants (B, C, T, H, KC, WIN) = (4, 512, 1024, 8, 64, 4)
#define Bdim 4
#define Cdim 512
#define Tdim 1024
#define Hn   8
#define KCd  64

typedef __attribute__((ext_vector_type(8))) short bf16x8;   // 8 bf16 = 4 VGPR
typedef __attribute__((ext_vector_type(4))) float f32x4;    // MFMA C/D

__device__ __forceinline__ unsigned short f32_bf16_rne(float f) {
    unsigned u = __float_as_uint(f);
    u += 0x7FFFu + ((u >> 16) & 1u);
    return (unsigned short)(u >> 16);
}
__device__ __forceinline__ float bf16_f32(unsigned short h) {
    return __uint_as_float(((unsigned)h) << 16);
}

// FRAG-MAJOR attn-plane layouts (R8, measured good):
//  row-type (Q,K): g=(t>>4)*2+(c>>5), lane=((c>>3)&3)*16+(t&15), e=c&7
//  col-type (V):   g=(c>>4)*2+(t>>5), lane=((t>>3)&3)*16+(c&15), e=t&7
__device__ __forceinline__ int off_row(int row, int c) {
    return (((row >> 4) * 2 + (c >> 5)) << 9)
         + (((((c >> 3) & 3) << 4) + (row & 15)) << 3) + (c & 7);
}
__device__ __forceinline__ int off_col(int c, int j) {
    return (((c >> 4) * 2 + (j >> 5)) << 9)
         + (((((j >> 3) & 3) << 4) + (c & 15)) << 3) + (j & 7);
}
// LDS 64x64 tile XOR swizzle (attention's P round-trip only)
__device__ __forceinline__ int sw(int row, int col) {
    return (row << 6) + ((((col >> 3) ^ (row & 7)) << 3) | (col & 7));
}
__device__ __forceinline__ bf16x8 fragld(const unsigned short* a, int row, int kstep, int quad) {
    return *(const bf16x8*)&a[(row << 6) + ((((kstep << 2) | quad) ^ (row & 7)) << 3)];
}

// Device-scope grid barrier. Valid: grid=512 blocks at guaranteed 2 blocks/CU
// (launch_bounds caps VGPR<=256, LDS 30.7KB) -> all blocks co-resident.
// acq_rel RMW chain + threadfence gives cross-XCD visibility (wbl2/inv).
__device__ __forceinline__ void grid_barrier(unsigned* cnt, unsigned* flag, unsigned target) {
    __syncthreads();
    if (threadIdx.x == 0) {
        __threadfence();
        if (__hip_atomic_fetch_add(cnt, 1u, __ATOMIC_ACQ_REL, __HIP_MEMORY_SCOPE_AGENT) == target - 1u)
            __hip_atomic_store(flag, 1u, __ATOMIC_RELEASE, __HIP_MEMORY_SCOPE_AGENT);
        while (__hip_atomic_load(flag, __ATOMIC_ACQUIRE, __HIP_MEMORY_SCOPE_AGENT) == 0u)
            __builtin_amdgcn_s_sleep(2);
        __threadfence();
    }
    __syncthreads();
}

// ---------------------------------------------------------------------------
// MEGA kernel: P1 QKV projection -> attn planes | barrier | P2 flash attn
// -> fp32 ctx | barrier | P3 out-projection. One dispatch total.
// ---------------------------------------------------------------------------
__global__ __launch_bounds__(256, 2) void mega_kernel(
    const float* __restrict__ x,
    const float* __restrict__ wq, const float* __restrict__ bq,
    const float* __restrict__ wk, const float* __restrict__ bk,
    const float* __restrict__ wv, const float* __restrict__ bv,
    const float* __restrict__ wo, const float* __restrict__ bo,
    const float* __restrict__ ek, const float* __restrict__ ev,
    unsigned short* __restrict__ qhi, unsigned short* __restrict__ qlo,
    unsigned short* __restrict__ khi, unsigned short* __restrict__ klo,
    unsigned short* __restrict__ vhi, unsigned short* __restrict__ vlo,
    float* __restrict__ cbuf, float* __restrict__ out,
    unsigned* __restrict__ bar)
{
    __shared__ alignas(16) unsigned char smem[30720];

    const int tid = threadIdx.x;
    const int bid = blockIdx.x;
    const int lane = tid & 63, wid = tid >> 6;
    const int l15 = lane & 15, quad = lane >> 4;

    // =====================================================================
    // Phase 1: QKV projection (R8 gemm3_mfma mode-0). 768 jobs on 512 blocks.
    // =====================================================================
    {
        unsigned short* Whi = (unsigned short*)smem;   // [128][40]
        unsigned short* Wlo = Whi + 5120;
        unsigned short* Xhi = Wlo + 5120;              // [64][40]
        unsigned short* Xlo = Xhi + 2560;

        const int wk4 = (tid & 7) * 4;
        const int wmr = tid >> 3;
        const int xn  = tid & 63;
        const int xo  = tid >> 6;
        const int wm = (wid & 1) * 64, wn = (wid >> 1) * 32;

        for (int pass = 0; pass < 2; ++pass) {
            if (pass == 1 && bid >= 256) break;
            const int job = pass == 0 ? bid : bid + 512;
            const int xcd = job & 7, slot = job >> 3;
            const int stripe = (xcd << 3) | (slot / 12);
            const int by = slot % 12;
            const int bx = stripe & 15;
            const int b  = stripe >> 4;

            const int m_tile = by * 128;
            const int sel = m_tile >> 9;
            const float* W  = sel == 0 ? wq : (sel == 1 ? wk : wv);
            const float* Bv = sel == 0 ? bq : (sel == 1 ? bk : bv);
            const int m0 = m_tile & 511;
            const int n0 = bx * 64;
            const float* Xb = x + (size_t)b * Cdim * Tdim;

            f32x4 acc[4][2];
            #pragma unroll
            for (int i = 0; i < 4; ++i)
                #pragma unroll
                for (int j = 0; j < 2; ++j) acc[i][j] = (f32x4){0.f, 0.f, 0.f, 0.f};

            for (int k0 = 0; k0 < Cdim; k0 += 32) {
                __syncthreads();
                #pragma unroll
                for (int p = 0; p < 4; ++p) {
                    const int m = wmr + p * 32;
                    float4 wv4 = *(const float4*)(W + (size_t)(m0 + m) * Cdim + k0 + wk4);
                    ushort4 hi, lo;
                    hi.x = f32_bf16_rne(wv4.x); lo.x = f32_bf16_rne(wv4.x - bf16_f32(hi.x));
                    hi.y = f32_bf16_rne(wv4.y); lo.y = f32_bf16_rne(wv4.y - bf16_f32(hi.y));
                    hi.z = f32_bf16_rne(wv4.z); lo.z = f32_bf16_rne(wv4.z - bf16_f32(hi.z));
                    hi.w = f32_bf16_rne(wv4.w); lo.w = f32_bf16_rne(wv4.w - bf16_f32(hi.w));
                    *(ushort4*)&Whi[m * 40 + wk4] = hi;
                    *(ushort4*)&Wlo[m * 40 + wk4] = lo;
                }
                {
                    float xv[8];
                    #pragma unroll
                    for (int kk = 0; kk < 8; ++kk)
                        xv[kk] = Xb[(size_t)(k0 + xo * 8 + kk) * Tdim + n0 + xn];
                    ushort4 hi0, hi1, lo0, lo1;
                    unsigned short h;
                    h = f32_bf16_rne(xv[0]); hi0.x = h; lo0.x = f32_bf16_rne(xv[0] - bf16_f32(h));
                    h = f32_bf16_rne(xv[1]); hi0.y = h; lo0.y = f32_bf16_rne(xv[1] - bf16_f32(h));
                    h = f32_bf16_rne(xv[2]); hi0.z = h; lo0.z = f32_bf16_rne(xv[2] - bf16_f32(h));
                    h = f32_bf16_rne(xv[3]); hi0.w = h; lo0.w = f32_bf16_rne(xv[3] - bf16_f32(h));
                    h = f32_bf16_rne(xv[4]); hi1.x = h; lo1.x = f32_bf16_rne(xv[4] - bf16_f32(h));
                    h = f32_bf16_rne(xv[5]); hi1.y = h; lo1.y = f32_bf16_rne(xv[5] - bf16_f32(h));
                    h = f32_bf16_rne(xv[6]); hi1.z = h; lo1.z = f32_bf16_rne(xv[6] - bf16_f32(h));
                    h = f32_bf16_rne(xv[7]); hi1.w = h; lo1.w = f32_bf16_rne(xv[7] - bf16_f32(h));
                    *(ushort4*)&Xhi[xn * 40 + xo * 8]     = hi0;
                    *(ushort4*)&Xhi[xn * 40 + xo * 8 + 4] = hi1;
                    *(ushort4*)&Xlo[xn * 40 + xo * 8]     = lo0;
                    *(ushort4*)&Xlo[xn * 40 + xo * 8 + 4] = lo1;
                }
                __syncthreads();

                bf16x8 ahi[4], alo[4], bhi[2], blo[2];
                #pragma unroll
                for (int mt = 0; mt < 4; ++mt) {
                    ahi[mt] = *(const bf16x8*)&Whi[(wm + mt * 16 + l15) * 40 + quad * 8];
                    alo[mt] = *(const bf16x8*)&Wlo[(wm + mt * 16 + l15) * 40 + quad * 8];
                }
                #pragma unroll
                for (int nt = 0; nt < 2; ++nt) {
                    bhi[nt] = *(const bf16x8*)&Xhi[(wn + nt * 16 + l15) * 40 + quad * 8];
                    blo[nt] = *(const bf16x8*)&Xlo[(wn + nt * 16 + l15) * 40 + quad * 8];
                }
                #pragma unroll
                for (int mt = 0; mt < 4; ++mt)
                    #pragma unroll
                    for (int nt = 0; nt < 2; ++nt) {
                        f32x4 c = acc[mt][nt];
                        c = __builtin_amdgcn_mfma_f32_16x16x32_bf16(ahi[mt], bhi[nt], c, 0, 0, 0);
                        c = __builtin_amdgcn_mfma_f32_16x16x32_bf16(ahi[mt], blo[nt], c, 0, 0, 0);
                        c = __builtin_amdgcn_mfma_f32_16x16x32_bf16(alo[mt], bhi[nt], c, 0, 0, 0);
                        acc[mt][nt] = c;
                    }
            }

            // ---- epilogue: frag-major attn planes ----
            if (sel < 2) {
                unsigned short* phi = sel == 0 ? qhi : khi;
                unsigned short* plo = sel == 0 ? qlo : klo;
                #pragma unroll
                for (int mt = 0; mt < 4; ++mt) {
                    const int mv = m0 + wm + mt * 16 + quad * 4;
                    const int head = mv >> 6, c0 = mv & 63;
                    float bb[4];
                    #pragma unroll
                    for (int r = 0; r < 4; ++r) bb[r] = Bv[mv + r];
                    #pragma unroll
                    for (int nt = 0; nt < 2; ++nt) {
                        const int t = n0 + wn + nt * 16 + l15;
                        const int tile = t >> 6, r_ = t & 63;
                        const size_t off = (((size_t)(b * Hn + head) * 16 + tile) << 12)
                                         + (size_t)off_row(r_, c0);
                        ushort4 h4, l4;
                        const float v0 = acc[mt][nt][0] + bb[0];
                        const float v1 = acc[mt][nt][1] + bb[1];
                        const float v2 = acc[mt][nt][2] + bb[2];
                        const float v3 = acc[mt][nt][3] + bb[3];
                        h4.x = f32_bf16_rne(v0); l4.x = f32_bf16_rne(v0 - bf16_f32(h4.x));
                        h4.y = f32_bf16_rne(v1); l4.y = f32_bf16_rne(v1 - bf16_f32(h4.y));
                        h4.z = f32_bf16_rne(v2); l4.z = f32_bf16_rne(v2 - bf16_f32(h4.z));
                        h4.w = f32_bf16_rne(v3); l4.w = f32_bf16_rne(v3 - bf16_f32(h4.w));
                        *(ushort4*)(phi + off) = h4;
                        *(ushort4*)(plo + off) = l4;
                    }
                }
            } else {
                #pragma unroll
                for (int mt = 0; mt < 4; ++mt) {
                    const int mv = m0 + wm + mt * 16 + quad * 4;
                    const int head = mv >> 6;
                    float bb[4];
                    #pragma unroll
                    for (int r = 0; r < 4; ++r) bb[r] = Bv[mv + r];
                    #pragma unroll
                    for (int nt = 0; nt < 2; ++nt) {
                        const int t = n0 + wn + nt * 16 + l15;
                        const int tile = t >> 6, jl = t & 63;
                        const size_t tb = ((size_t)(b * Hn + head) * 16 + tile) << 12;
                        #pragma unroll
                        for (int r = 0; r < 4; ++r) {
                            const int cr = (mv & 63) + r;
                            const float v = acc[mt][nt][r] + bb[r];
                            const unsigned short h = f32_bf16_rne(v);
                            const size_t off = tb + off_col(cr, jl);
                            vhi[off] = h;
                            vlo[off] = f32_bf16_rne(v - bf16_f32(h));
                        }
                    }
                }
            }
        }
    }

    grid_barrier(bar + 0, bar + 1, 512u);

    // =====================================================================
    // Phase 2: barrier-free MFMA flash attention (R8), fp32 ctx out.
    // =====================================================================
    {
        unsigned short* psh = (unsigned short*)smem;   // 4096
        unsigned short* psl = psh + 4096;
        float* rk  = (float*)(psl + 4096);             // 576
        float* evs = rk + 576;

        int it, h, b;
        {
            const int n = bid;
            const int xcd = n & 7, slot = n >> 3;
            const int pair = (xcd << 2) | (slot >> 4);
            it = slot & 15;
            b = pair >> 3;
            h = pair & 7;
        }
        const int i0 = it * 64;
        const int w = wid;
        const int m_blk = w * 16 + l15;
        const int lo8 = lane << 3;

        const size_t bh16 = (size_t)(b * Hn + h) * 16;
        float* ctxb = cbuf + ((size_t)b * Cdim + h * KCd) * Tdim;

        bf16x8 qfh[2], qfl[2];
        {
            const unsigned short* qth = qhi + ((bh16 + it) << 12);
            const unsigned short* qtl = qlo + ((bh16 + it) << 12);
            #pragma unroll
            for (int ks = 0; ks < 2; ++ks) {
                qfh[ks] = *(const bf16x8*)(qth + (((w << 1) | ks) << 9) + lo8);
                qfl[ks] = *(const bf16x8*)(qtl + (((w << 1) | ks) << 9) + lo8);
            }
        }

        bf16x8 ekh[2], ekl[2];
        #pragma unroll
        for (int ks = 0; ks < 2; ++ks) {
            #pragma unroll
            for (int j = 0; j < 8; ++j) { ekh[ks][j] = 0; ekl[ks][j] = 0; }
            if (l15 < 9) {
                #pragma unroll
                for (int j = 0; j < 8; ++j) {
                    const float v = ek[l15 * 64 + ks * 32 + quad * 8 + j];
                    const unsigned short hh = f32_bf16_rne(v);
                    ekh[ks][j] = (short)hh;
                    ekl[ks][j] = (short)f32_bf16_rne(v - bf16_f32(hh));
                }
            }
        }

        {
            f32x4 rkD = (f32x4){0.f, 0.f, 0.f, 0.f};
            #pragma unroll
            for (int ks = 0; ks < 2; ++ks) {
                rkD = __builtin_amdgcn_mfma_f32_16x16x32_bf16(qfh[ks], ekh[ks], rkD, 0, 0, 0);
                rkD = __builtin_amdgcn_mfma_f32_16x16x32_bf16(qfh[ks], ekl[ks], rkD, 0, 0, 0);
                rkD = __builtin_amdgcn_mfma_f32_16x16x32_bf16(qfl[ks], ekh[ks], rkD, 0, 0, 0);
            }
            if (l15 < 9) {
                #pragma unroll
                for (int r = 0; r < 4; ++r)
                    rk[(w * 16 + quad * 4 + r) * 9 + l15] = rkD[r];
            }
        }
        for (int idx = tid; idx < 576; idx += 256) evs[idx] = ev[idx];
        __syncthreads();   // rk/evs visible (block-local)

        float m_run = -1e30f, l_run = 0.f;
        f32x4 Oc[4];
        #pragma unroll
        for (int ct = 0; ct < 4; ++ct) Oc[ct] = (f32x4){0.f, 0.f, 0.f, 0.f};

        const unsigned short* kh0 = khi + (bh16 << 12);
        const unsigned short* kl0 = klo + (bh16 << 12);
        const unsigned short* vh0 = vhi + (bh16 << 12);
        const unsigned short* vl0 = vlo + (bh16 << 12);

        for (int t = 0; t < 16; ++t) {
            const int j0 = t << 6;
            const size_t tb = (size_t)t << 12;
            const unsigned short* kht = kh0 + tb;
            const unsigned short* klt = kl0 + tb;
            const unsigned short* vht = vh0 + tb;
            const unsigned short* vlt = vl0 + tb;

            bf16x8 vbh[2][4], vbl[2][4];
            #pragma unroll
            for (int ks = 0; ks < 2; ++ks)
                #pragma unroll
                for (int ct = 0; ct < 4; ++ct) {
                    vbh[ks][ct] = *(const bf16x8*)(vht + (((ct << 1) | ks) << 9) + lo8);
                    vbl[ks][ct] = *(const bf16x8*)(vlt + (((ct << 1) | ks) << 9) + lo8);
                }

            f32x4 Sc[4];
            #pragma unroll
            for (int jt = 0; jt < 4; ++jt) Sc[jt] = (f32x4){0.f, 0.f, 0.f, 0.f};
            #pragma unroll
            for (int ks = 0; ks < 2; ++ks) {
                bf16x8 ah[4], al[4];
                #pragma unroll
                for (int jt = 0; jt < 4; ++jt) {
                    ah[jt] = *(const bf16x8*)(kht + (((jt << 1) | ks) << 9) + lo8);
                    al[jt] = *(const bf16x8*)(klt + (((jt << 1) | ks) << 9) + lo8);
                }
                #pragma unroll
                for (int jt = 0; jt < 4; ++jt) {
                    Sc[jt] = __builtin_amdgcn_mfma_f32_16x16x32_bf16(ah[jt], qfh[ks], Sc[jt], 0, 0, 0);
                    Sc[jt] = __builtin_amdgcn_mfma_f32_16x16x32_bf16(ah[jt], qfl[ks], Sc[jt], 0, 0, 0);
                    Sc[jt] = __builtin_amdgcn_mfma_f32_16x16x32_bf16(al[jt], qfh[ks], Sc[jt], 0, 0, 0);
                }
            }

            const int dt = j0 - i0;
            const bool diag = (dt >= -67 && dt <= 67);
            if (diag) {
                #pragma unroll
                for (int jt = 0; jt < 4; ++jt) {
                    const int db = dt + jt * 16 + quad * 4 - m_blk;
                    #pragma unroll
                    for (int r = 0; r < 4; ++r) {
                        const int d = db + r;
                        if ((unsigned)(d + 4) <= 8u) Sc[jt][r] += rk[m_blk * 9 + d + 4];
                    }
                }
            }

            float mt = -1e30f;
            #pragma unroll
            for (int jt = 0; jt < 4; ++jt)
                #pragma unroll
                for (int r = 0; r < 4; ++r) {
                    Sc[jt][r] *= 0.125f;
                    mt = fmaxf(mt, Sc[jt][r]);
                }
            mt = fmaxf(mt, __shfl_xor(mt, 16));
            mt = fmaxf(mt, __shfl_xor(mt, 32));
            const float mn = fmaxf(m_run, mt);
            const float alpha = __expf(m_run - mn);
            float rs = 0.f;
            #pragma unroll
            for (int jt = 0; jt < 4; ++jt)
                #pragma unroll
                for (int r = 0; r < 4; ++r) {
                    const float e = __expf(Sc[jt][r] - mn);
                    Sc[jt][r] = e;
                    rs += e;
                }
            rs += __shfl_xor(rs, 16);
            rs += __shfl_xor(rs, 32);
            l_run = l_run * alpha + rs;
            m_run = mn;

            #pragma unroll
            for (int jt = 0; jt < 4; ++jt) {
                ushort4 ph, pl;
                ph.x = f32_bf16_rne(Sc[jt][0]); pl.x = f32_bf16_rne(Sc[jt][0] - bf16_f32(ph.x));
                ph.y = f32_bf16_rne(Sc[jt][1]); pl.y = f32_bf16_rne(Sc[jt][1] - bf16_f32(ph.y));
                ph.z = f32_bf16_rne(Sc[jt][2]); pl.z = f32_bf16_rne(Sc[jt][2] - bf16_f32(ph.z));
                ph.w = f32_bf16_rne(Sc[jt][3]); pl.w = f32_bf16_rne(Sc[jt][3] - bf16_f32(ph.w));
                const int o = sw(m_blk, jt * 16 + quad * 4);
                *(ushort4*)&psh[o] = ph;
                *(ushort4*)&psl[o] = pl;
            }
            // no barrier: wave reads only its own 16 P rows

            const float al0 = __shfl(alpha, quad * 4 + 0);
            const float al1 = __shfl(alpha, quad * 4 + 1);
            const float al2 = __shfl(alpha, quad * 4 + 2);
            const float al3 = __shfl(alpha, quad * 4 + 3);
            #pragma unroll
            for (int ct = 0; ct < 4; ++ct) {
                Oc[ct][0] *= al0; Oc[ct][1] *= al1; Oc[ct][2] *= al2; Oc[ct][3] *= al3;
            }
            #pragma unroll
            for (int ks = 0; ks < 2; ++ks) {
                bf16x8 pah = fragld(psh, m_blk, ks, quad);
                bf16x8 pal = fragld(psl, m_blk, ks, quad);
                #pragma unroll
                for (int ct = 0; ct < 4; ++ct) {
                    Oc[ct] = __builtin_amdgcn_mfma_f32_16x16x32_bf16(pah, vbh[ks][ct], Oc[ct], 0, 0, 0);
                    Oc[ct] = __builtin_amdgcn_mfma_f32_16x16x32_bf16(pah, vbl[ks][ct], Oc[ct], 0, 0, 0);
                    Oc[ct] = __builtin_amdgcn_mfma_f32_16x16x32_bf16(pal, vbh[ks][ct], Oc[ct], 0, 0, 0);
                }
            }

            if (diag) {
                #pragma unroll
                for (int r = 0; r < 4; ++r) {
                    const int mrow = w * 16 + quad * 4 + r;
                    const int ig = i0 + mrow;
                    #pragma unroll
                    for (int e = 0; e < 9; ++e) {
                        const int jl = ig + e - 4 - j0;
                        if ((unsigned)jl < 64u) {
                            const int o = sw(mrow, jl);
                            const float p = bf16_f32(psh[o]) + bf16_f32(psl[o]);
                            #pragma unroll
                            for (int ct = 0; ct < 4; ++ct)
                                Oc[ct][r] += p * evs[e * 64 + ct * 16 + l15];
                        }
                    }
                }
            }
        }

        const float rlv = 1.f / l_run;
        const float rl0 = __shfl(rlv, quad * 4 + 0);
        const float rl1 = __shfl(rlv, quad * 4 + 1);
        const float rl2 = __shfl(rlv, quad * 4 + 2);
        const float rl3 = __shfl(rlv, quad * 4 + 3);
        #pragma unroll
        for (int ct = 0; ct < 4; ++ct) {
            float4 o4;
            o4.x = Oc[ct][0] * rl0;
            o4.y = Oc[ct][1] * rl1;
            o4.z = Oc[ct][2] * rl2;
            o4.w = Oc[ct][3] * rl3;
            *(float4*)(ctxb + (size_t)(ct * 16 + l15) * Tdim + i0 + w * 16 + quad * 4) = o4;
        }
    }

    grid_barrier(bar + 2, bar + 3, 512u);

    // =====================================================================
    // Phase 3: output projection (R8 gemm3_mfma mode-1). 256 jobs, bid<256.
    // =====================================================================
    if (bid < 256) {
        unsigned short* Whi = (unsigned short*)smem;
        unsigned short* Wlo = Whi + 5120;
        unsigned short* Xhi = Wlo + 5120;
        unsigned short* Xlo = Xhi + 2560;

        const int wk4 = (tid & 7) * 4;
        const int wmr = tid >> 3;
        const int xn  = tid & 63;
        const int xo  = tid >> 6;
        const int wm = (wid & 1) * 64, wn = (wid >> 1) * 32;

        const int xcd = bid & 7, slot = bid >> 3;
        const int stripe = (xcd << 3) | (slot >> 2);
        const int by = slot & 3;
        const int bx = stripe & 15;
        const int b  = stripe >> 4;
        const int m0 = by * 128;
        const int n0 = bx * 64;
        const float* Xb = cbuf + (size_t)b * Cdim * Tdim;

        f32x4 acc[4][2];
        #pragma unroll
        for (int i = 0; i < 4; ++i)
            #pragma unroll
            for (int j = 0; j < 2; ++j) acc[i][j] = (f32x4){0.f, 0.f, 0.f, 0.f};

        for (int k0 = 0; k0 < Cdim; k0 += 32) {
            __syncthreads();
            #pragma unroll
            for (int p = 0; p < 4; ++p) {
                const int m = wmr + p * 32;
                float4 wv4 = *(const float4*)(wo + (size_t)(m0 + m) * Cdim + k0 + wk4);
                ushort4 hi, lo;
                hi.x = f32_bf16_rne(wv4.x); lo.x = f32_bf16_rne(wv4.x - bf16_f32(hi.x));
                hi.y = f32_bf16_rne(wv4.y); lo.y = f32_bf16_rne(wv4.y - bf16_f32(hi.y));
                hi.z = f32_bf16_rne(wv4.z); lo.z = f32_bf16_rne(wv4.z - bf16_f32(hi.z));
                hi.w = f32_bf16_rne(wv4.w); lo.w = f32_bf16_rne(wv4.w - bf16_f32(hi.w));
                *(ushort4*)&Whi[m * 40 + wk4] = hi;
                *(ushort4*)&Wlo[m * 40 + wk4] = lo;
            }
            {
                float xv[8];
                #pragma unroll
                for (int kk = 0; kk < 8; ++kk)
                    xv[kk] = Xb[(size_t)(k0 + xo * 8 + kk) * Tdim + n0 + xn];
                ushort4 hi0, hi1, lo0, lo1;
                unsigned short h;
                h = f32_bf16_rne(xv[0]); hi0.x = h; lo0.x = f32_bf16_rne(xv[0] - bf16_f32(h));
                h = f32_bf16_rne(xv[1]); hi0.y = h; lo0.y = f32_bf16_rne(xv[1] - bf16_f32(h));
                h = f32_bf16_rne(xv[2]); hi0.z = h; lo0.z = f32_bf16_rne(xv[2] - bf16_f32(h));
                h = f32_bf16_rne(xv[3]); hi0.w = h; lo0.w = f32_bf16_rne(xv[3] - bf16_f32(h));
                h = f32_bf16_rne(xv[4]); hi1.x = h; lo1.x = f32_bf16_rne(xv[4] - bf16_f32(h));
                h = f32_bf16_rne(xv[5]); hi1.y = h; lo1.y = f32_bf16_rne(xv[5] - bf16_f32(h));
                h = f32_bf16_rne(xv[6]); hi1.z = h; lo1.z = f32_bf16_rne(xv[6] - bf16_f32(h));
                h = f32_bf16_rne(xv[7]); hi1.w = h; lo1.w = f32_bf16_rne(xv[7] - bf16_f32(h));
                *(ushort4*)&Xhi[xn * 40 + xo * 8]     = hi0;
                *(ushort4*)&Xhi[xn * 40 + xo * 8 + 4] = hi1;
                *(ushort4*)&Xlo[xn * 40 + xo * 8]     = lo0;
                *(ushort4*)&Xlo[xn * 40 + xo * 8 + 4] = lo1;
            }
            __syncthreads();

            bf16x8 ahi[4], alo[4], bhi[2], blo[2];
            #pragma unroll
            for (int mt = 0; mt < 4; ++mt) {
                ahi[mt] = *(const bf16x8*)&Whi[(wm + mt * 16 + l15) * 40 + quad * 8];
                alo[mt] = *(const bf16x8*)&Wlo[(wm + mt * 16 + l15) * 40 + quad * 8];
            }
            #pragma unroll
            for (int nt = 0; nt < 2; ++nt) {
                bhi[nt] = *(const bf16x8*)&Xhi[(wn + nt * 16 + l15) * 40 + quad * 8];
                blo[nt] = *(const bf16x8*)&Xlo[(wn + nt * 16 + l15) * 40 + quad * 8];
            }
            #pragma unroll
            for (int mt = 0; mt < 4; ++mt)
                #pragma unroll
                for (int nt = 0; nt < 2; ++nt) {
                    f32x4 c = acc[mt][nt];
                    c = __builtin_amdgcn_mfma_f32_16x16x32_bf16(ahi[mt], bhi[nt], c, 0, 0, 0);
                    c = __builtin_amdgcn_mfma_f32_16x16x32_bf16(ahi[mt], blo[nt], c, 0, 0, 0);
                    c = __builtin_amdgcn_mfma_f32_16x16x32_bf16(alo[mt], bhi[nt], c, 0, 0, 0);
                    acc[mt][nt] = c;
                }
        }

        float* Ob = out + (size_t)b * Cdim * Tdim;
        #pragma unroll
        for (int mt = 0; mt < 4; ++mt) {
            const int mb = m0 + wm + mt * 16 + quad * 4;
            float bb[4];
            #pragma unroll
            for (int r = 0; r < 4; ++r) bb[r] = bo[mb + r];
            #pragma unroll
            for (int nt = 0; nt < 2; ++nt) {
                const int t = n0 + wn + nt * 16 + l15;
                #pragma unroll
                for (int r = 0; r < 4; ++r)
                    Ob[(size_t)(mb + r) * Tdim + t] = acc[mt][nt][r] + bb[r];
            }
        }
    }
}

// ---------------------------------------------------------------------------
extern "C" void kernel_launch(void* const* d_in, const int* in_sizes, int n_in,
                              void* d_out, int out_size, void* d_ws, size_t ws_size,
                              hipStream_t stream) {
    const float* x  = (const float*)d_in[0];
    const float* wq = (const float*)d_in[1];
    const float* bq = (const float*)d_in[2];
    const float* wk = (const float*)d_in[3];
    const float* bk = (const float*)d_in[4];
    const float* wv = (const float*)d_in[5];
    const float* bv = (const float*)d_in[6];
    const float* wo = (const float*)d_in[7];
    const float* bo = (const float*)d_in[8];
    const float* ek = (const float*)d_in[9];
    const float* ev = (const float*)d_in[10];
    float* out = (float*)d_out;

    const size_t plane = (size_t)Bdim * Cdim * Tdim;  // 2M elements
    unsigned short* qhi = (unsigned short*)d_ws;
    unsigned short* qlo = qhi + plane;
    unsigned short* khi = qlo + plane;
    unsigned short* klo = khi + plane;
    unsigned short* vhi = klo + plane;
    unsigned short* vlo = vhi + plane;
    float* cbuf = (float*)(vlo + plane);              // 8 MB fp32
    unsigned* bar = (unsigned*)(cbuf + plane);        // 4 counters/flags

    hipMemsetAsync(bar, 0, 64, stream);

    mega_kernel<<<dim3(512), 256, 0, stream>>>(
        x, wq, bq, wk, bk, wv, bv, wo, bo, ek, ev,
        qhi, qlo, khi, klo, vhi, vlo, cbuf, out, bar);
}

// Round 11
// 181.064 us; speedup vs baseline: 2.4215x; 2.4215x over previous
//
#include <hip/hip_runtime.h>
#include <hip/hip_bf16.h>

// Problem constants (B, C, T, H, KC, WIN) = (4, 512, 1024, 8, 64, 4)
#define Bdim 4
#define Cdim 512
#define Tdim 1024
#define Hn   8
#define KCd  64

typedef __attribute__((ext_vector_type(8))) short bf16x8;   // 8 bf16 = 4 VGPR
typedef __attribute__((ext_vector_type(4))) float f32x4;    // MFMA C/D

__device__ __forceinline__ unsigned short f32_bf16_rne(float f) {
    unsigned u = __float_as_uint(f);
    u += 0x7FFFu + ((u >> 16) & 1u);
    return (unsigned short)(u >> 16);
}
__device__ __forceinline__ float bf16_f32(unsigned short h) {
    return __uint_as_float(((unsigned)h) << 16);
}
__device__ __forceinline__ void split8(const float* f, bf16x8& h8, bf16x8& l8) {
    #pragma unroll
    for (int e = 0; e < 8; ++e) {
        const unsigned short hh = f32_bf16_rne(f[e]);
        h8[e] = (short)hh;
        l8[e] = (short)f32_bf16_rne(f[e] - bf16_f32(hh));
    }
}

// LDS 64x64 tile XOR swizzle (only attention's P round-trip)
__device__ __forceinline__ int sw(int row, int col) {
    return (row << 6) + ((((col >> 3) ^ (row & 7)) << 3) | (col & 7));
}
__device__ __forceinline__ bf16x8 fragld(const unsigned short* a, int row, int kstep, int quad) {
    return *(const bf16x8*)&a[(row << 6) + ((((kstep << 2) | quad) ^ (row & 7)) << 3)];
}

// ---------------------------------------------------------------------------
// FRAG-MAJOR plane layouts (hi/lo pre-split), as validated in R8/R9:
//  A-plane (stacked [wq;wk;wv;wo], 2048 rows x 512 k):
//    [mtile16:128][kt:16][lane:64][e:8]; elem(m,k): lane=((k>>3)&3)*16+(m&15), e=k&7
//  B-plane (X / ctx, per batch n=1024, k=512):
//    [b*64+ntile16][kt:16][lane:64][e:8]; elem(n,k): lane=((k>>3)&3)*16+(n&15), e=k&7
//  Attn planes per (b,h), 16 time-tiles of 64x64:
//    row-type (Q,K): g=(t>>4)*2+(c>>5), lane=((c>>3)&3)*16+(t&15), e=c&7
//    col-type (V):   g=(c>>4)*2+(t>>5), lane=((t>>3)&3)*16+(c&15), e=t&7
// ---------------------------------------------------------------------------

// prep: one-time fp32 -> hi/lo split into A/B planes (R9, measured good)
__global__ __launch_bounds__(256) void prep_kernel(
    const float* __restrict__ wq, const float* __restrict__ wk,
    const float* __restrict__ wv, const float* __restrict__ wo,
    const float* __restrict__ x,
    unsigned short* __restrict__ WAhi, unsigned short* __restrict__ WAlo,
    unsigned short* __restrict__ XBhi, unsigned short* __restrict__ XBlo)
{
    const int w = threadIdx.x >> 6, lane = threadIdx.x & 63;
    const int l15 = lane & 15, quad = lane >> 4;
    const int task = blockIdx.x * 4 + w;

    if (task < 2048) {
        const int mtile = task >> 4, kt = task & 15;
        const int sel = mtile >> 5;
        const float* W = sel == 0 ? wq : (sel == 1 ? wk : (sel == 2 ? wv : wo));
        const int row = (mtile & 31) * 16 + l15;
        const float* p = W + (size_t)row * Cdim + kt * 32 + quad * 8;
        float f[8];
        *(float4*)&f[0] = *(const float4*)p;
        *(float4*)&f[4] = *(const float4*)(p + 4);
        bf16x8 h8, l8;
        split8(f, h8, l8);
        const size_t base = (size_t)task * 512 + lane * 8;
        *(bf16x8*)(WAhi + base) = h8;
        *(bf16x8*)(WAlo + base) = l8;
    } else {
        const int t2 = task - 2048;
        const int b = t2 >> 10, ntile = (t2 >> 4) & 63, kt = t2 & 15;
        const float* Xb = x + (size_t)b * Cdim * Tdim;
        const int n = ntile * 16 + l15;
        const int k0 = kt * 32 + quad * 8;
        float f[8];
        #pragma unroll
        for (int e = 0; e < 8; ++e) f[e] = Xb[(size_t)(k0 + e) * Tdim + n];
        bf16x8 h8, l8;
        split8(f, h8, l8);
        const size_t base = (size_t)t2 * 512 + lane * 8;
        *(bf16x8*)(XBhi + base) = h8;
        *(bf16x8*)(XBlo + base) = l8;
    }
}

// ---------------------------------------------------------------------------
// QKV GEMM: barrier-free, zero-LDS, dbuf. Wave = 64m x 32n x 512k.
// 3072 wave-jobs -> 768 blocks = 3 blocks/CU (12 waves/CU).
// XCD-clustered: 16 (b,n32) columns per XCD share B stripes in that L2.
// ---------------------------------------------------------------------------
__global__ __launch_bounds__(256, 3) void gemm_qkv(
    const unsigned short* __restrict__ Ahi, const unsigned short* __restrict__ Alo,
    const unsigned short* __restrict__ Bhi, const unsigned short* __restrict__ Blo,
    const float* __restrict__ bq, const float* __restrict__ bk, const float* __restrict__ bv,
    unsigned short* __restrict__ qhi, unsigned short* __restrict__ qlo,
    unsigned short* __restrict__ khi, unsigned short* __restrict__ klo,
    unsigned short* __restrict__ vhi, unsigned short* __restrict__ vlo)
{
    const int tid = threadIdx.x;
    const int w = tid >> 6, lane = tid & 63;
    const int l15 = lane & 15, quad = lane >> 4;
    const int lo8 = lane << 3;

    const int id = blockIdx.x;
    const int xcd = id & 7, slot = id >> 3;     // slot 0..95
    const int col = xcd * 16 + slot / 6;        // 0..127 = (b, n32)
    const int mg  = slot % 6;
    const int b = col >> 5, n32 = col & 31;
    const int m64 = mg * 4 + w;                 // 0..23 stacked q/k/v
    const int sel = m64 >> 3;
    const int mtb = m64 * 4;                    // mtile16 base (q:0-31 k:32-63 v:64-95)
    const int ntb = b * 64 + n32 * 2;

    f32x4 acc[4][2];
    #pragma unroll
    for (int i = 0; i < 4; ++i)
        #pragma unroll
        for (int j = 0; j < 2; ++j) acc[i][j] = (f32x4){0.f, 0.f, 0.f, 0.f};

    bf16x8 Ah[2][4], Al[2][4], Bh[2][2], Bl[2][2];
    #pragma unroll
    for (int mt = 0; mt < 4; ++mt) {
        const size_t o = (size_t)(mtb + mt) * 8192 + lo8;
        Ah[0][mt] = *(const bf16x8*)(Ahi + o);
        Al[0][mt] = *(const bf16x8*)(Alo + o);
    }
    #pragma unroll
    for (int nt = 0; nt < 2; ++nt) {
        const size_t o = (size_t)(ntb + nt) * 8192 + lo8;
        Bh[0][nt] = *(const bf16x8*)(Bhi + o);
        Bl[0][nt] = *(const bf16x8*)(Blo + o);
    }

    for (int kt = 0; kt < 16; ++kt) {
        const int cur = kt & 1, nxt = cur ^ 1;
        if (kt < 15) {
            const int kn = (kt + 1) * 512;
            #pragma unroll
            for (int mt = 0; mt < 4; ++mt) {
                const size_t o = (size_t)(mtb + mt) * 8192 + kn + lo8;
                Ah[nxt][mt] = *(const bf16x8*)(Ahi + o);
                Al[nxt][mt] = *(const bf16x8*)(Alo + o);
            }
            #pragma unroll
            for (int nt = 0; nt < 2; ++nt) {
                const size_t o = (size_t)(ntb + nt) * 8192 + kn + lo8;
                Bh[nxt][nt] = *(const bf16x8*)(Bhi + o);
                Bl[nxt][nt] = *(const bf16x8*)(Blo + o);
            }
        }
        #pragma unroll
        for (int mt = 0; mt < 4; ++mt)
            #pragma unroll
            for (int nt = 0; nt < 2; ++nt) {
                f32x4 c = acc[mt][nt];
                c = __builtin_amdgcn_mfma_f32_16x16x32_bf16(Ah[cur][mt], Bh[cur][nt], c, 0, 0, 0);
                c = __builtin_amdgcn_mfma_f32_16x16x32_bf16(Ah[cur][mt], Bl[cur][nt], c, 0, 0, 0);
                c = __builtin_amdgcn_mfma_f32_16x16x32_bf16(Al[cur][mt], Bh[cur][nt], c, 0, 0, 0);
                acc[mt][nt] = c;
            }
    }

    // ---- epilogue: D[m=quad*4+r (channel)][n=l15 (time)] -> attn planes ----
    const int head = m64 & 7;
    const size_t hbase = ((size_t)(b * Hn + head) * 16) << 12;
    if (sel < 2) {
        const float* Bv = sel == 0 ? bq : bk;
        unsigned short* ph = sel == 0 ? qhi : khi;
        unsigned short* pl = sel == 0 ? qlo : klo;
        #pragma unroll
        for (int mt = 0; mt < 4; ++mt) {
            const int c0 = mt * 16 + quad * 4;          // channel-in-head base
            float bb[4];
            #pragma unroll
            for (int r = 0; r < 4; ++r) bb[r] = Bv[head * 64 + c0 + r];
            const int lane_out = (((c0 >> 3) & 3) << 4) + l15;
            const int e0 = c0 & 7;                      // 0 or 4
            const int cg = c0 >> 5;
            #pragma unroll
            for (int nt = 0; nt < 2; ++nt) {
                const int tile = n32 >> 1;
                const int rhi = (n32 & 1) * 2 + nt;     // (t&63)>>4
                const int g = rhi * 2 + cg;
                const size_t off = hbase + ((size_t)tile << 12) + g * 512
                                 + (size_t)lane_out * 8 + e0;
                ushort4 h4, l4;
                #pragma unroll
                for (int r = 0; r < 4; ++r) {
                    const float v = acc[mt][nt][r] + bb[r];
                    const unsigned short hh = f32_bf16_rne(v);
                    ((unsigned short*)&h4)[r] = hh;
                    ((unsigned short*)&l4)[r] = f32_bf16_rne(v - bf16_f32(hh));
                }
                *(ushort4*)(ph + off) = h4;
                *(ushort4*)(pl + off) = l4;
            }
        }
    } else {
        #pragma unroll
        for (int mt = 0; mt < 4; ++mt) {
            const int c0 = mt * 16 + quad * 4;
            float bb[4];
            #pragma unroll
            for (int r = 0; r < 4; ++r) bb[r] = bv[head * 64 + c0 + r];
            #pragma unroll
            for (int nt = 0; nt < 2; ++nt) {
                const int t = n32 * 32 + nt * 16 + l15;
                const int tile = t >> 6, jl = t & 63;
                const int jg = jl >> 5, lanej = ((jl >> 3) & 3) << 4;
                const int e = jl & 7;
                const size_t tb = hbase + ((size_t)tile << 12);
                #pragma unroll
                for (int r = 0; r < 4; ++r) {
                    const int c = c0 + r;
                    const int g = mt * 2 + jg;          // c>>4 == mt here
                    const int lane_v = lanej + (c & 15);
                    const float v = acc[mt][nt][r] + bb[r];
                    const unsigned short hh = f32_bf16_rne(v);
                    const size_t off = tb + g * 512 + (size_t)lane_v * 8 + e;
                    vhi[off] = hh;
                    vlo[off] = f32_bf16_rne(v - bf16_f32(hh));
                }
            }
        }
    }
}

// ---------------------------------------------------------------------------
// Out-projection GEMM: barrier-free, zero-LDS, dbuf. Wave = 32m x 32n x 512k.
// 2048 wave-jobs -> 512 blocks = 2 blocks/CU (every CU active).
// A = Wo rows (mtile16 96..127), B = ctx planes from attention.
// ---------------------------------------------------------------------------
__global__ __launch_bounds__(256) void gemm_out(
    const unsigned short* __restrict__ Ahi, const unsigned short* __restrict__ Alo,
    const unsigned short* __restrict__ Bhi, const unsigned short* __restrict__ Blo,
    const float* __restrict__ bo, float* __restrict__ out)
{
    const int tid = threadIdx.x;
    const int w = tid >> 6, lane = tid & 63;
    const int l15 = lane & 15, quad = lane >> 4;
    const int lo8 = lane << 3;

    const int id = blockIdx.x;
    const int xcd = id & 7, slot = id >> 3;     // slot 0..63
    const int col = xcd * 16 + (slot >> 2);     // 0..127 = (b, n32)
    const int mg  = slot & 3;
    const int b = col >> 5, n32 = col & 31;
    const int m32 = mg * 4 + w;                 // 0..15
    const int mtb = 96 + m32 * 2;               // Wo mtile16 base
    const int ntb = b * 64 + n32 * 2;

    f32x4 acc[2][2];
    #pragma unroll
    for (int i = 0; i < 2; ++i)
        #pragma unroll
        for (int j = 0; j < 2; ++j) acc[i][j] = (f32x4){0.f, 0.f, 0.f, 0.f};

    bf16x8 Ah[2][2], Al[2][2], Bh[2][2], Bl[2][2];
    #pragma unroll
    for (int mt = 0; mt < 2; ++mt) {
        const size_t o = (size_t)(mtb + mt) * 8192 + lo8;
        Ah[0][mt] = *(const bf16x8*)(Ahi + o);
        Al[0][mt] = *(const bf16x8*)(Alo + o);
    }
    #pragma unroll
    for (int nt = 0; nt < 2; ++nt) {
        const size_t o = (size_t)(ntb + nt) * 8192 + lo8;
        Bh[0][nt] = *(const bf16x8*)(Bhi + o);
        Bl[0][nt] = *(const bf16x8*)(Blo + o);
    }

    for (int kt = 0; kt < 16; ++kt) {
        const int cur = kt & 1, nxt = cur ^ 1;
        if (kt < 15) {
            const int kn = (kt + 1) * 512;
            #pragma unroll
            for (int mt = 0; mt < 2; ++mt) {
                const size_t o = (size_t)(mtb + mt) * 8192 + kn + lo8;
                Ah[nxt][mt] = *(const bf16x8*)(Ahi + o);
                Al[nxt][mt] = *(const bf16x8*)(Alo + o);
            }
            #pragma unroll
            for (int nt = 0; nt < 2; ++nt) {
                const size_t o = (size_t)(ntb + nt) * 8192 + kn + lo8;
                Bh[nxt][nt] = *(const bf16x8*)(Bhi + o);
                Bl[nxt][nt] = *(const bf16x8*)(Blo + o);
            }
        }
        #pragma unroll
        for (int mt = 0; mt < 2; ++mt)
            #pragma unroll
            for (int nt = 0; nt < 2; ++nt) {
                f32x4 c = acc[mt][nt];
                c = __builtin_amdgcn_mfma_f32_16x16x32_bf16(Ah[cur][mt], Bh[cur][nt], c, 0, 0, 0);
                c = __builtin_amdgcn_mfma_f32_16x16x32_bf16(Ah[cur][mt], Bl[cur][nt], c, 0, 0, 0);
                c = __builtin_amdgcn_mfma_f32_16x16x32_bf16(Al[cur][mt], Bh[cur][nt], c, 0, 0, 0);
                acc[mt][nt] = c;
            }
    }

    float* Ob = out + (size_t)b * Cdim * Tdim;
    #pragma unroll
    for (int mt = 0; mt < 2; ++mt) {
        const int m = m32 * 32 + mt * 16 + quad * 4;
        float bb[4];
        #pragma unroll
        for (int r = 0; r < 4; ++r) bb[r] = bo[m + r];
        #pragma unroll
        for (int nt = 0; nt < 2; ++nt) {
            const int t = n32 * 32 + nt * 16 + l15;
            #pragma unroll
            for (int r = 0; r < 4; ++r)
                Ob[(size_t)(m + r) * Tdim + t] = acc[mt][nt][r] + bb[r];
        }
    }
}

// ---------------------------------------------------------------------------
// Barrier-free MFMA flash attention (R8/R9 structure, measured 57 us).
// Epilogue writes ctx as B-operand frag-major hi/lo planes (R9, verified).
// ---------------------------------------------------------------------------
__global__ __launch_bounds__(256) void attn_mfma(
    const unsigned short* __restrict__ qhi, const unsigned short* __restrict__ qlo,
    const unsigned short* __restrict__ khi, const unsigned short* __restrict__ klo,
    const unsigned short* __restrict__ vhi, const unsigned short* __restrict__ vlo,
    const float* __restrict__ ek,   // [9,64]
    const float* __restrict__ ev,   // [9,64]
    unsigned short* __restrict__ cxhi, unsigned short* __restrict__ cxlo)
{
    __shared__ alignas(16) unsigned short psh[4096], psl[4096];
    __shared__ float rk[576];
    __shared__ float evs[576];

    const int tid = threadIdx.x;
    int it, h, b;
    {
        const int n = blockIdx.x;
        const int xcd = n & 7, slot = n >> 3;
        const int pair = (xcd << 2) | (slot >> 4);
        it = slot & 15;
        b = pair >> 3;
        h = pair & 7;
    }
    const int i0 = it * 64;
    const int lane = tid & 63, w = tid >> 6;
    const int l15 = lane & 15, quad = lane >> 4;
    const int m_blk = w * 16 + l15;
    const int lo8 = lane << 3;

    const size_t bh16 = (size_t)(b * Hn + h) * 16;

    bf16x8 qfh[2], qfl[2];
    {
        const unsigned short* qth = qhi + ((bh16 + it) << 12);
        const unsigned short* qtl = qlo + ((bh16 + it) << 12);
        #pragma unroll
        for (int ks = 0; ks < 2; ++ks) {
            qfh[ks] = *(const bf16x8*)(qth + (((w << 1) | ks) << 9) + lo8);
            qfl[ks] = *(const bf16x8*)(qtl + (((w << 1) | ks) << 9) + lo8);
        }
    }

    bf16x8 ekh[2], ekl[2];
    #pragma unroll
    for (int ks = 0; ks < 2; ++ks) {
        #pragma unroll
        for (int j = 0; j < 8; ++j) { ekh[ks][j] = 0; ekl[ks][j] = 0; }
        if (l15 < 9) {
            #pragma unroll
            for (int j = 0; j < 8; ++j) {
                const float v = ek[l15 * 64 + ks * 32 + quad * 8 + j];
                const unsigned short hh = f32_bf16_rne(v);
                ekh[ks][j] = (short)hh;
                ekl[ks][j] = (short)f32_bf16_rne(v - bf16_f32(hh));
            }
        }
    }

    {
        f32x4 rkD = (f32x4){0.f, 0.f, 0.f, 0.f};
        #pragma unroll
        for (int ks = 0; ks < 2; ++ks) {
            rkD = __builtin_amdgcn_mfma_f32_16x16x32_bf16(qfh[ks], ekh[ks], rkD, 0, 0, 0);
            rkD = __builtin_amdgcn_mfma_f32_16x16x32_bf16(qfh[ks], ekl[ks], rkD, 0, 0, 0);
            rkD = __builtin_amdgcn_mfma_f32_16x16x32_bf16(qfl[ks], ekh[ks], rkD, 0, 0, 0);
        }
        if (l15 < 9) {
            #pragma unroll
            for (int r = 0; r < 4; ++r)
                rk[(w * 16 + quad * 4 + r) * 9 + l15] = rkD[r];
        }
    }
    for (int idx = tid; idx < 576; idx += 256) evs[idx] = ev[idx];
    __syncthreads();   // the ONLY barrier

    float m_run = -1e30f, l_run = 0.f;
    f32x4 Oc[4];
    #pragma unroll
    for (int ct = 0; ct < 4; ++ct) Oc[ct] = (f32x4){0.f, 0.f, 0.f, 0.f};

    const unsigned short* kh0 = khi + (bh16 << 12);
    const unsigned short* kl0 = klo + (bh16 << 12);
    const unsigned short* vh0 = vhi + (bh16 << 12);
    const unsigned short* vl0 = vlo + (bh16 << 12);

    for (int t = 0; t < 16; ++t) {
        const int j0 = t << 6;
        const size_t tb = (size_t)t << 12;
        const unsigned short* kht = kh0 + tb;
        const unsigned short* klt = kl0 + tb;
        const unsigned short* vht = vh0 + tb;
        const unsigned short* vlt = vl0 + tb;

        bf16x8 vbh[2][4], vbl[2][4];
        #pragma unroll
        for (int ks = 0; ks < 2; ++ks)
            #pragma unroll
            for (int ct = 0; ct < 4; ++ct) {
                vbh[ks][ct] = *(const bf16x8*)(vht + (((ct << 1) | ks) << 9) + lo8);
                vbl[ks][ct] = *(const bf16x8*)(vlt + (((ct << 1) | ks) << 9) + lo8);
            }

        f32x4 Sc[4];
        #pragma unroll
        for (int jt = 0; jt < 4; ++jt) Sc[jt] = (f32x4){0.f, 0.f, 0.f, 0.f};
        #pragma unroll
        for (int ks = 0; ks < 2; ++ks) {
            bf16x8 ah[4], al[4];
            #pragma unroll
            for (int jt = 0; jt < 4; ++jt) {
                ah[jt] = *(const bf16x8*)(kht + (((jt << 1) | ks) << 9) + lo8);
                al[jt] = *(const bf16x8*)(klt + (((jt << 1) | ks) << 9) + lo8);
            }
            #pragma unroll
            for (int jt = 0; jt < 4; ++jt) {
                Sc[jt] = __builtin_amdgcn_mfma_f32_16x16x32_bf16(ah[jt], qfh[ks], Sc[jt], 0, 0, 0);
                Sc[jt] = __builtin_amdgcn_mfma_f32_16x16x32_bf16(ah[jt], qfl[ks], Sc[jt], 0, 0, 0);
                Sc[jt] = __builtin_amdgcn_mfma_f32_16x16x32_bf16(al[jt], qfh[ks], Sc[jt], 0, 0, 0);
            }
        }

        const int dt = j0 - i0;
        const bool diag = (dt >= -67 && dt <= 67);
        if (diag) {
            #pragma unroll
            for (int jt = 0; jt < 4; ++jt) {
                const int db = dt + jt * 16 + quad * 4 - m_blk;
                #pragma unroll
                for (int r = 0; r < 4; ++r) {
                    const int d = db + r;
                    if ((unsigned)(d + 4) <= 8u) Sc[jt][r] += rk[m_blk * 9 + d + 4];
                }
            }
        }

        float mt = -1e30f;
        #pragma unroll
        for (int jt = 0; jt < 4; ++jt)
            #pragma unroll
            for (int r = 0; r < 4; ++r) {
                Sc[jt][r] *= 0.125f;
                mt = fmaxf(mt, Sc[jt][r]);
            }
        mt = fmaxf(mt, __shfl_xor(mt, 16));
        mt = fmaxf(mt, __shfl_xor(mt, 32));
        const float mn = fmaxf(m_run, mt);
        const float alpha = __expf(m_run - mn);
        float rs = 0.f;
        #pragma unroll
        for (int jt = 0; jt < 4; ++jt)
            #pragma unroll
            for (int r = 0; r < 4; ++r) {
                const float e = __expf(Sc[jt][r] - mn);
                Sc[jt][r] = e;
                rs += e;
            }
        rs += __shfl_xor(rs, 16);
        rs += __shfl_xor(rs, 32);
        l_run = l_run * alpha + rs;
        m_run = mn;

        #pragma unroll
        for (int jt = 0; jt < 4; ++jt) {
            ushort4 ph, pl;
            ph.x = f32_bf16_rne(Sc[jt][0]); pl.x = f32_bf16_rne(Sc[jt][0] - bf16_f32(ph.x));
            ph.y = f32_bf16_rne(Sc[jt][1]); pl.y = f32_bf16_rne(Sc[jt][1] - bf16_f32(ph.y));
            ph.z = f32_bf16_rne(Sc[jt][2]); pl.z = f32_bf16_rne(Sc[jt][2] - bf16_f32(ph.z));
            ph.w = f32_bf16_rne(Sc[jt][3]); pl.w = f32_bf16_rne(Sc[jt][3] - bf16_f32(ph.w));
            const int o = sw(m_blk, jt * 16 + quad * 4);
            *(ushort4*)&psh[o] = ph;
            *(ushort4*)&psl[o] = pl;
        }
        // no barrier: wave reads only its own 16 P rows

        const float al0 = __shfl(alpha, quad * 4 + 0);
        const float al1 = __shfl(alpha, quad * 4 + 1);
        const float al2 = __shfl(alpha, quad * 4 + 2);
        const float al3 = __shfl(alpha, quad * 4 + 3);
        #pragma unroll
        for (int ct = 0; ct < 4; ++ct) {
            Oc[ct][0] *= al0; Oc[ct][1] *= al1; Oc[ct][2] *= al2; Oc[ct][3] *= al3;
        }
        #pragma unroll
        for (int ks = 0; ks < 2; ++ks) {
            bf16x8 pah = fragld(psh, m_blk, ks, quad);
            bf16x8 pal = fragld(psl, m_blk, ks, quad);
            #pragma unroll
            for (int ct = 0; ct < 4; ++ct) {
                Oc[ct] = __builtin_amdgcn_mfma_f32_16x16x32_bf16(pah, vbh[ks][ct], Oc[ct], 0, 0, 0);
                Oc[ct] = __builtin_amdgcn_mfma_f32_16x16x32_bf16(pah, vbl[ks][ct], Oc[ct], 0, 0, 0);
                Oc[ct] = __builtin_amdgcn_mfma_f32_16x16x32_bf16(pal, vbh[ks][ct], Oc[ct], 0, 0, 0);
            }
        }

        if (diag) {
            #pragma unroll
            for (int r = 0; r < 4; ++r) {
                const int mrow = w * 16 + quad * 4 + r;
                const int ig = i0 + mrow;
                #pragma unroll
                for (int e = 0; e < 9; ++e) {
                    const int jl = ig + e - 4 - j0;
                    if ((unsigned)jl < 64u) {
                        const int o = sw(mrow, jl);
                        const float p = bf16_f32(psh[o]) + bf16_f32(psl[o]);
                        #pragma unroll
                        for (int ct = 0; ct < 4; ++ct)
                            Oc[ct][r] += p * evs[e * 64 + ct * 16 + l15];
                    }
                }
            }
        }
    }

    // ---- epilogue: normalize, write ctx B-operand frag-major hi/lo planes ----
    const float rlv = 1.f / l_run;
    float rl[4];
    rl[0] = __shfl(rlv, quad * 4 + 0);
    rl[1] = __shfl(rlv, quad * 4 + 1);
    rl[2] = __shfl(rlv, quad * 4 + 2);
    rl[3] = __shfl(rlv, quad * 4 + 3);
    const int ntile16 = it * 4 + w;
    const int e = l15 & 7;
    #pragma unroll
    for (int ct = 0; ct < 4; ++ct) {
        const int cl = ct * 16 + l15;                    // channel within head
        const int ktc = h * 2 + (cl >> 5);
        const int lane_c = (((ct * 2 + (l15 >> 3)) & 3) << 4) + quad * 4;   // + r
        const size_t base = (((size_t)(b * 64 + ntile16)) * 16 + ktc) * 512;
        #pragma unroll
        for (int r = 0; r < 4; ++r) {
            const float v = Oc[ct][r] * rl[r];
            const unsigned short hh = f32_bf16_rne(v);
            const size_t off = base + (size_t)(lane_c + r) * 8 + e;
            cxhi[off] = hh;
            cxlo[off] = f32_bf16_rne(v - bf16_f32(hh));
        }
    }
}

// ---------------------------------------------------------------------------
extern "C" void kernel_launch(void* const* d_in, const int* in_sizes, int n_in,
                              void* d_out, int out_size, void* d_ws, size_t ws_size,
                              hipStream_t stream) {
    const float* x  = (const float*)d_in[0];
    const float* wq = (const float*)d_in[1];
    const float* bq = (const float*)d_in[2];
    const float* wk = (const float*)d_in[3];
    const float* bk = (const float*)d_in[4];
    const float* wv = (const float*)d_in[5];
    const float* bv = (const float*)d_in[6];
    const float* wo = (const float*)d_in[7];
    const float* bo = (const float*)d_in[8];
    const float* ek = (const float*)d_in[9];
    const float* ev = (const float*)d_in[10];
    float* out = (float*)d_out;

    const size_t PW = 2048u * 512u;          // stacked-W plane elements
    const size_t PX = 4u * 1024u * 512u;     // X / ctx / attn plane elements
    unsigned short* WAhi = (unsigned short*)d_ws;
    unsigned short* WAlo = WAhi + PW;
    unsigned short* XBhi = WAlo + PW;
    unsigned short* XBlo = XBhi + PX;
    unsigned short* qhi  = XBlo + PX;
    unsigned short* qlo  = qhi + PX;
    unsigned short* khi  = qlo + PX;
    unsigned short* klo  = khi + PX;
    unsigned short* vhi  = klo + PX;
    unsigned short* vlo  = vhi + PX;
    unsigned short* cxhi = vlo + PX;
    unsigned short* cxlo = cxhi + PX;

    // one-time split/convert of W and X into frag-major planes
    prep_kernel<<<dim3(1536), 256, 0, stream>>>(
        wq, wk, wv, wo, x, WAhi, WAlo, XBhi, XBlo);

    // QKV projection: 768 blocks (3/CU), barrier-free dbuf -> attn planes
    gemm_qkv<<<dim3(768), 256, 0, stream>>>(
        WAhi, WAlo, XBhi, XBlo, bq, bk, bv,
        qhi, qlo, khi, klo, vhi, vlo);

    // barrier-free MFMA flash attention -> ctx B-operand planes
    attn_mfma<<<dim3(512), 256, 0, stream>>>(
        qhi, qlo, khi, klo, vhi, vlo, ek, ev, cxhi, cxlo);

    // output projection: 512 blocks (2/CU), A=Wo, B=ctx -> natural fp32 out
    gemm_out<<<dim3(512), 256, 0, stream>>>(
        WAhi, WAlo, cxhi, cxlo, bo, out);
}